// Round 10
// baseline (141.313 us; speedup 1.0000x reference)
//
#include <hip/hip_runtime.h>
#include <hip/hip_bf16.h>
#include <stdint.h>

// Galerkin self-attention, fused:
//   out = seq @ (wq.T @ blockdiag_h(kv[b,h]) @ wo.T) + bo
//   kv[b,h] = (1/S) * LN(k)_h^T @ LN(v)_h,   k = seq@wk.T, v = seq@wv.T
// v10: r6 structure restored (fragment-major bf16 weights; r9's inline-fp32
//      weight loads were uncoalesced -> kv 55us). kv restructured for
//      occupancy: 32KB LDS (5 blocks/CU vs 2): LN -> registers (r1's kln/vln),
//      two-phase kT/vT in the dead x-region, two-phase outer product.
//      P fragment layout unchanged (algebra-identical). wqT built in red.
// ws layout (bytes):
//   0        wkf bf16 fragment-major [w8][kk][n][lane][8]
//   131072   wvf bf16 fragment-major
//   262144   wqT bf16 [256 i][256 j]        (written by gka_red blocks 0-15)
//   524288   kvf f32 [4 b][4 h][4096 frag]  (fragment order, by gka_red)
//   1310720  wcf bf16 fragment-major [b][o6][kk][n][lane][8]
// d_out doubles as scratch for P = bf16 partials [4 b][128 p][4 h][4096 frag]
// (16.8MB of the 33.5MB output buffer); gka_out fully overwrites d_out last.

#define EMBED 256
#define SEQ   8192
#define LN_EPS 1e-5f

using bf16x8 = __attribute__((ext_vector_type(8))) short;
using bf16x4 = __attribute__((ext_vector_type(4))) short;
using f32x4  = __attribute__((ext_vector_type(4))) float;

static __device__ __forceinline__ short f2bf(float f) {
  __hip_bfloat16 h = __float2bfloat16(f);
  return __builtin_bit_cast(short, h);
}
static __device__ __forceinline__ float bf2f(uint32_t u) {
  return __uint_as_float(u << 16);
}
static __device__ __forceinline__ bf16x8 cvt8(f32x4 a, f32x4 b) {
  bf16x8 v;
  v[0] = f2bf(a[0]); v[1] = f2bf(a[1]); v[2] = f2bf(a[2]); v[3] = f2bf(a[3]);
  v[4] = f2bf(b[0]); v[5] = f2bf(b[1]); v[6] = f2bf(b[2]); v[7] = f2bf(b[3]);
  return v;
}

#define MFMA16(a, b, c) __builtin_amdgcn_mfma_f32_16x16x32_bf16((a), (b), (c), 0, 0, 0)

// Stage ROWS x 256 fp32 rows -> bf16 LDS [ROWS][256], rows 512B, byte^=(row&7)<<4
template <int ROWS>
static __device__ __forceinline__ void stage_x(char* smem, const float* __restrict__ src, int tid) {
#pragma unroll
  for (int i = 0; i < ROWS / 8; ++i) {
    int g = tid + i * 256;              // 16B-granule index
    int row = g >> 5, c16 = g & 31;
    const f32x4* p = (const f32x4*)(src + row * EMBED + c16 * 8);
    *(bf16x8*)(smem + row * 512 + ((c16 * 16) ^ ((row & 7) << 4))) = cvt8(p[0], p[1]);
  }
}

// ---------------- prep: wk/wv -> fragment-major bf16 ----------------
__global__ void gka_prep(const float* __restrict__ wk, const float* __restrict__ wv,
                         unsigned short* __restrict__ wkf, unsigned short* __restrict__ wvf) {
  int blk = blockIdx.x, tid = threadIdx.x;
  int g = (blk & 31) * 256 + tid;         // [0, 8192) granule of 8 bf16
  const float* W = (blk < 32) ? wk : wv;
  unsigned short* D = (blk < 32) ? wkf : wvf;
  int w8 = g >> 11, kk = (g >> 8) & 7, n = (g >> 6) & 3, ln = g & 63;
  int row = w8 * 64 + n * 16 + (ln & 15);
  int c0 = kk * 32 + (ln >> 4) * 8;
  const f32x4* p = (const f32x4*)(W + row * 256 + c0);
  *(bf16x8*)(D + g * 8) = cvt8(p[0], p[1]);
}

// ---------------- pass A: k,v GEMM (merged) + LN->regs + 2-phase kv partial ----------
__global__ __launch_bounds__(256, 4)
void gka_kv(const float* __restrict__ seq,
            const unsigned short* __restrict__ wkf, const unsigned short* __restrict__ wvf,
            const float* __restrict__ lkg, const float* __restrict__ lkb,
            const float* __restrict__ lvg, const float* __restrict__ lvb,
            unsigned short* __restrict__ P) {
  __shared__ char smem[32768];            // x-tile; after GEMM: [kT0 8K][vT0 8K][kT1 8K][vT1 8K]
  const int tid = threadIdx.x;
  const int lane = tid & 63;
  const int wid = tid >> 6;               // wave = head
  const int l15 = lane & 15, l4 = lane >> 4, l7 = lane & 7;
  const int tile = blockIdx.x;            // 512 blocks, 64 tokens each
  const int b = tile >> 7;
  const int ptile = tile & 127;

  stage_x<64>(smem, seq + (size_t)(b * SEQ + ptile * 64) * EMBED, tid);
  __syncthreads();

  // merged k+v GEMM: one pass over x, fragment-major bf16 weight streams
  f32x4 acck[4][4], accv[4][4];
#pragma unroll
  for (int m = 0; m < 4; ++m)
#pragma unroll
    for (int n = 0; n < 4; ++n) { acck[m][n] = (f32x4)0.0f; accv[m][n] = (f32x4)0.0f; }

#pragma unroll
  for (int kk = 0; kk < 8; ++kk) {        // K = 256, steps of 32
    bf16x8 af[4], bwk[4], bwv[4];
#pragma unroll
    for (int m = 0; m < 4; ++m) {
      int row = m * 16 + l15;
      af[m] = *(const bf16x8*)(smem + row * 512 + ((kk * 64 + l4 * 16) ^ (l7 << 4)));
    }
#pragma unroll
    for (int n = 0; n < 4; ++n) {         // fragment-major: 512B coalesced per wave
      size_t off = (((wid * 8 + kk) * 4 + n) * 64 + lane) << 3;
      bwk[n] = *(const bf16x8*)(wkf + off);
      bwv[n] = *(const bf16x8*)(wvf + off);
    }
#pragma unroll
    for (int m = 0; m < 4; ++m)
#pragma unroll
      for (int n = 0; n < 4; ++n) {
        acck[m][n] = MFMA16(af[m], bwk[n], acck[m][n]);
        accv[m][n] = MFMA16(af[m], bwv[n], accv[m][n]);
      }
  }

  __syncthreads();                        // all x-tile LDS reads done; x region reusable

  // LN over this wave's 64 head-cols -> packed registers (no LDS)
  bf16x4 kln[16], vln[16];                // [m*4+n], 4 token-rows each
#pragma unroll
  for (int mat = 0; mat < 2; ++mat) {
    const f32x4 (*acc)[4] = mat ? accv : acck;     // mat is unroll-static
    const float* gp = mat ? lvg : lkg;
    const float* bp = mat ? lvb : lkb;
    float gv[4], bv[4];
#pragma unroll
    for (int n = 0; n < 4; ++n) { gv[n] = gp[n * 16 + l15]; bv[n] = bp[n * 16 + l15]; }
#pragma unroll
    for (int m = 0; m < 4; ++m) {
      float mu[4], rs[4];
#pragma unroll
      for (int r = 0; r < 4; ++r) {
        float s1 = 0.f, s2 = 0.f;
#pragma unroll
        for (int n = 0; n < 4; ++n) { float x = acc[m][n][r]; s1 += x; s2 += x * x; }
#pragma unroll
        for (int msk = 1; msk < 16; msk <<= 1) {
          s1 += __shfl_xor(s1, msk);
          s2 += __shfl_xor(s2, msk);
        }
        mu[r] = s1 * (1.f / 64.f);
        float var = s2 * (1.f / 64.f) - mu[r] * mu[r];
        rs[r] = rsqrtf(var + LN_EPS);
      }
#pragma unroll
      for (int n = 0; n < 4; ++n) {
        bf16x4 pk;
#pragma unroll
        for (int r = 0; r < 4; ++r)
          pk[r] = f2bf((acc[m][n][r] - mu[r]) * rs[r] * gv[n] + bv[n]);
        if (mat == 0) kln[m * 4 + n] = pk; else vln[m * 4 + n] = pk;
      }
    }
  }

  // kv partial: two phases, heads {0,1} then {2,3}; 32KB LDS total
#pragma unroll
  for (int p = 0; p < 2; ++p) {
    if ((wid >> 1) == p) {                // waves owning heads 2p, 2p+1 write tiles
      int hs = wid & 1;
#pragma unroll
      for (int m = 0; m < 4; ++m)
#pragma unroll
        for (int n = 0; n < 4; ++n) {
          int d = n * 16 + l15;           // d&7 == l7
          int sb = m * 32 + l4 * 8;       // byte in row, s0 = m*16 + l4*4
          int off = hs * 16384 + d * 128 + (sb ^ (l7 << 4));
          *(bf16x4*)(smem + off) = kln[m * 4 + n];
          *(bf16x4*)(smem + off + 8192) = vln[m * 4 + n];
        }
    }
    __syncthreads();
    int hs = wid >> 1;                    // head slot this wave computes
    int feh = wid & 1;                    // e-half
    f32x4 kvacc[4][2];
#pragma unroll
    for (int fd = 0; fd < 4; ++fd) { kvacc[fd][0] = (f32x4)0.0f; kvacc[fd][1] = (f32x4)0.0f; }
#pragma unroll
    for (int kk = 0; kk < 2; ++kk) {      // 64 tokens = 2 K-steps
      bf16x8 ak[4], b2[2];
#pragma unroll
      for (int fd = 0; fd < 4; ++fd) {
        int d = fd * 16 + l15;
        ak[fd] = *(const bf16x8*)(smem + hs * 16384 + d * 128 +
                                  ((kk * 64 + l4 * 16) ^ (l7 << 4)));
      }
#pragma unroll
      for (int c = 0; c < 2; ++c) {
        int e = (feh * 2 + c) * 16 + l15;
        b2[c] = *(const bf16x8*)(smem + hs * 16384 + 8192 + e * 128 +
                                 ((kk * 64 + l4 * 16) ^ (l7 << 4)));
      }
#pragma unroll
      for (int fd = 0; fd < 4; ++fd)
#pragma unroll
        for (int c = 0; c < 2; ++c)
          kvacc[fd][c] = MFMA16(ak[fd], b2[c], kvacc[fd][c]);
    }
    int hg = p * 2 + hs;
    // store P in fragment order (identical flat layout to r6): coalesced 512B
    unsigned short* Ph = P + ((size_t)((b * 128 + ptile) * 4 + hg) << 12);
#pragma unroll
    for (int fd = 0; fd < 4; ++fd)
#pragma unroll
      for (int c = 0; c < 2; ++c) {
        bf16x4 pk;
#pragma unroll
        for (int r = 0; r < 4; ++r) pk[r] = f2bf(kvacc[fd][c][r]);
        *(bf16x4*)(Ph + (fd * 4 + feh * 2 + c) * 256 + lane * 4) = pk;
      }
    __syncthreads();                      // before phase-1 overwrites tiles
  }
}

// ---------------- reduce: kvf = sum_p P;  blocks 0-15 also build wqT -----------------
__global__ __launch_bounds__(256)
void gka_red(const unsigned short* __restrict__ P, float* __restrict__ kvf,
             const float* __restrict__ wq, unsigned short* __restrict__ wqt) {
  __shared__ unsigned short T[64 * 66];
  int blk = blockIdx.x, tid = threadIdx.x;
  {
    int gtid = blk * 256 + tid;               // 131072 = 16384 quads x 8 chunks
    int chunk = gtid & 7;
    int qid = gtid >> 3;                      // (b<<12) | (h<<10) | t4
    int b = qid >> 12, h = (qid >> 10) & 3, t4 = qid & 1023;
    const unsigned short* p0 = P + ((size_t)(b * 512 + h) << 12) + t4 * 4;
    float s0 = 0.f, s1 = 0.f, s2 = 0.f, s3 = 0.f;
#pragma unroll
    for (int s = 0; s < 16; ++s) {
      int p = chunk * 16 + s;
      uint2 u = *(const uint2*)(p0 + ((size_t)p << 14));
      s0 += bf2f(u.x & 0xffffu); s1 += bf2f(u.x >> 16);
      s2 += bf2f(u.y & 0xffffu); s3 += bf2f(u.y >> 16);
    }
#pragma unroll
    for (int msk = 1; msk < 8; msk <<= 1) {
      s0 += __shfl_xor(s0, msk); s1 += __shfl_xor(s1, msk);
      s2 += __shfl_xor(s2, msk); s3 += __shfl_xor(s3, msk);
    }
    if (chunk == 0) {
      f32x4 r; r[0] = s0; r[1] = s1; r[2] = s2; r[3] = s3;
      *(f32x4*)(kvf + (qid << 2)) = r;
    }
  }

  if (blk < 16) {                         // 64x64 tile transpose wqt[i][j] = wq[j][i]
    int ti = blk >> 2, tj = blk & 3;
#pragma unroll
    for (int it = 0; it < 4; ++it) {
      int g = tid + it * 256;               // 1024 granules of 4 floats
      int jl = g >> 4, g4 = g & 15;
      f32x4 f = *(const f32x4*)(wq + (tj * 64 + jl) * 256 + ti * 64 + g4 * 4);
#pragma unroll
      for (int q = 0; q < 4; ++q) T[jl * 66 + g4 * 4 + q] = (unsigned short)f2bf(f[q]);
    }
    __syncthreads();
#pragma unroll
    for (int it = 0; it < 2; ++it) {
      int g = tid + it * 256;               // 512 output groups of 8
      int il = g >> 3, j8 = g & 7;
      bf16x8 v;
#pragma unroll
      for (int q = 0; q < 8; ++q) v[q] = (short)T[(j8 * 8 + q) * 66 + il];
      *(bf16x8*)(wqt + (ti * 64 + il) * 256 + tj * 64 + j8 * 8) = v;
    }
  }
}

// ---------------- pass B (merged m1+wc): per (b, o-half) block ----------------------
// phase 1: M1T[o_loc][j=h*64+d] = sum_e kv[b,h,d,e]/S * wo[o][h*64+e]  -> LDS (swz)
// phase 2: WcT frag-major: Wc[i][o] = sum_j wqT[i][j] * M1T[o_loc][j]
__global__ __launch_bounds__(512)
void gka_wc(const float* __restrict__ kvf, const float* __restrict__ wo,
            const unsigned short* __restrict__ wqt, unsigned short* __restrict__ wcf) {
  __shared__ char M1[65536];              // [128 o_loc][256 j] bf16, 512B rows, swz
  const int tid = threadIdx.x;
  const int lane = tid & 63;
  const int wid = tid >> 6;               // 8 waves
  const int l15 = lane & 15, l4 = lane >> 4;
  const int blk = blockIdx.x;             // 8 = 4b x 2 o-half
  const int b = blk >> 1, oh = blk & 1;
  const float invS = 1.f / (float)SEQ;

  // ---- phase 1: wave -> (wo_t = wid>>2 o-64-range, wj = wid&3 head) ----
  {
    const int wo_t = wid >> 2, wj = wid & 3;
    const float* kvh = kvf + ((b * 4 + wj) << 12);
    f32x4 acc[4][4];
#pragma unroll
    for (int m = 0; m < 4; ++m)
#pragma unroll
      for (int n = 0; n < 4; ++n) acc[m][n] = (f32x4)0.0f;

#pragma unroll
    for (int kk = 0; kk < 2; ++kk) {      // K = 64 (e)
      bf16x8 af[4], bw[4];
#pragma unroll
      for (int m = 0; m < 4; ++m) {
        // gather (d = m*16+l15, e = kk*32+l4*8+j) from kv fragment layout
        int base = (m * 4 + kk * 2 + (l4 >> 1)) * 256 +
                   ((l15 >> 2) * 16 + (l4 & 1) * 8) * 4 + (l15 & 3);
        bf16x8 v;
#pragma unroll
        for (int j = 0; j < 8; ++j) v[j] = f2bf(kvh[base + j * 4] * invS);
        af[m] = v;
      }
#pragma unroll
      for (int n = 0; n < 4; ++n) {
        int o = oh * 128 + wo_t * 64 + n * 16 + l15;
        const f32x4* wp = (const f32x4*)(wo + (size_t)o * 256 + wj * 64 + kk * 32 + l4 * 8);
        bw[n] = cvt8(wp[0], wp[1]);
      }
#pragma unroll
      for (int m = 0; m < 4; ++m)
#pragma unroll
        for (int n = 0; n < 4; ++n)
          acc[m][n] = MFMA16(af[m], bw[n], acc[m][n]);
    }
    // store to LDS M1T: row = o_loc, col j = wj*64 + m*16 + l4*4 + r (bf16x4), swz
#pragma unroll
    for (int m = 0; m < 4; ++m)
#pragma unroll
      for (int n = 0; n < 4; ++n) {
        int row = wo_t * 64 + n * 16 + l15;
        int jb = (wj * 64 + m * 16 + l4 * 4) * 2;
        bf16x4 pk;
#pragma unroll
        for (int r = 0; r < 4; ++r) pk[r] = f2bf(acc[m][n][r]);
        *(bf16x4*)(M1 + row * 512 + (jb ^ ((row & 7) << 4))) = pk;
      }
  }

  __syncthreads();

  // ---- phase 2: wave -> (wi = wid>>1 i-64-range, wo2 = wid&1 o-64-range) ----
  {
    const int wi = wid >> 1, wo2 = wid & 1;
    f32x4 acc[4][4];
#pragma unroll
    for (int m = 0; m < 4; ++m)
#pragma unroll
      for (int n = 0; n < 4; ++n) acc[m][n] = (f32x4)0.0f;

#pragma unroll
    for (int kk = 0; kk < 8; ++kk) {      // K = 256 (j)
      bf16x8 af[4], bw[4];
#pragma unroll
      for (int m = 0; m < 4; ++m) {
        int i = wi * 64 + m * 16 + l15;
        af[m] = *(const bf16x8*)(wqt + i * 256 + kk * 32 + l4 * 8);
      }
#pragma unroll
      for (int n = 0; n < 4; ++n) {
        int row = wo2 * 64 + n * 16 + l15;
        bw[n] = *(const bf16x8*)(M1 + row * 512 +
                                 ((kk * 64 + l4 * 16) ^ ((row & 7) << 4)));
      }
#pragma unroll
      for (int m = 0; m < 4; ++m)
#pragma unroll
        for (int n = 0; n < 4; ++n)
          acc[m][n] = MFMA16(af[m], bw[n], acc[m][n]);
    }
    // store to fragment-major wcf for gka_out
    const int o6 = oh * 2 + wo2;
#pragma unroll
    for (int m = 0; m < 4; ++m)
#pragma unroll
      for (int n = 0; n < 4; ++n) {
        int kko = wi * 2 + (m >> 1);
        int laneo = ((m & 1) * 2 + (l4 >> 1)) * 16 + l15;
        int jo = (l4 & 1) * 4;
        bf16x4 pk;
#pragma unroll
        for (int r = 0; r < 4; ++r) pk[r] = f2bf(acc[m][n][r]);
        *(bf16x4*)(wcf + ((size_t)b << 16) +
                   (((((o6 * 8 + kko) * 4 + n) * 64) + laneo) << 3) + jo) = pk;
      }
  }
}

// ---------------- pass C: out = seq @ Wc[b] + bo  (1024 x 32-token tiles, LDS) -------
__global__ __launch_bounds__(256, 4)
void gka_out(const float* __restrict__ seq, const unsigned short* __restrict__ wcf,
             const float* __restrict__ bo, float* __restrict__ out) {
  __shared__ char smem[16384];
  const int tid = threadIdx.x;
  const int lane = tid & 63;
  const int wid = tid >> 6;               // wave -> o-range (64 cols)
  const int l15 = lane & 15, l4 = lane >> 4, l7 = lane & 7;
  const int tile = blockIdx.x;            // 1024 = 4b x 256 tiles of 32 rows
  const int b = tile >> 8;
  const int srow = (tile & 255) * 32;

  stage_x<32>(smem, seq + (size_t)(b * SEQ + srow) * EMBED, tid);

  const unsigned short* Wf = wcf + ((size_t)b << 16);
  float bov[4];
#pragma unroll
  for (int n = 0; n < 4; ++n) bov[n] = bo[wid * 64 + n * 16 + l15];

  f32x4 acc[2][4];
#pragma unroll
  for (int m = 0; m < 2; ++m)
#pragma unroll
    for (int n = 0; n < 4; ++n) acc[m][n] = (f32x4)0.0f;

  __syncthreads();

#pragma unroll
  for (int kk = 0; kk < 8; ++kk) {        // K = 256, no barriers
    bf16x8 af[2], bw[4];
#pragma unroll
    for (int m = 0; m < 2; ++m) {
      int row = m * 16 + l15;
      af[m] = *(const bf16x8*)(smem + row * 512 + ((kk * 64 + l4 * 16) ^ (l7 << 4)));
    }
#pragma unroll
    for (int n = 0; n < 4; ++n)           // coalesced 512B per wave, L2-resident
      bw[n] = *(const bf16x8*)(Wf + ((((wid * 8 + kk) * 4 + n) * 64 + lane) << 3));
#pragma unroll
    for (int m = 0; m < 2; ++m)
#pragma unroll
      for (int n = 0; n < 4; ++n)
        acc[m][n] = MFMA16(af[m], bw[n], acc[m][n]);
  }

  float* dst = out + (size_t)(b * SEQ + srow) * EMBED;
#pragma unroll
  for (int m = 0; m < 2; ++m)
#pragma unroll
    for (int n = 0; n < 4; ++n)
#pragma unroll
      for (int r = 0; r < 4; ++r)
        dst[(size_t)(m * 16 + l4 * 4 + r) * EMBED + wid * 64 + n * 16 + l15] =
            acc[m][n][r] + bov[n];
}

extern "C" void kernel_launch(void* const* d_in, const int* in_sizes, int n_in,
                              void* d_out, int out_size, void* d_ws, size_t ws_size,
                              hipStream_t stream) {
  const float* seq = (const float*)d_in[0];
  const float* wq  = (const float*)d_in[1];
  const float* wk  = (const float*)d_in[2];
  const float* wv  = (const float*)d_in[3];
  const float* wo  = (const float*)d_in[4];
  const float* bo  = (const float*)d_in[5];
  const float* lkg = (const float*)d_in[6];
  const float* lkb = (const float*)d_in[7];
  const float* lvg = (const float*)d_in[8];
  const float* lvb = (const float*)d_in[9];
  float* out = (float*)d_out;
  char* ws = (char*)d_ws;

  unsigned short* wkf = (unsigned short*)(ws + 0);
  unsigned short* wvf = (unsigned short*)(ws + 131072);
  unsigned short* wqt = (unsigned short*)(ws + 262144);
  float*          kvf = (float*)(ws + 524288);
  unsigned short* wcf = (unsigned short*)(ws + 1310720);
  unsigned short* P   = (unsigned short*)d_out;   // 16.8MB partials, overwritten by gka_out

  gka_prep<<<64, 256, 0, stream>>>(wk, wv, wkf, wvf);
  gka_kv<<<512, 256, 0, stream>>>(seq, wkf, wvf, lkg, lkb, lvg, lvb, P);
  gka_red<<<512, 256, 0, stream>>>(P, kvf, wq, wqt);
  gka_wc<<<8, 512, 0, stream>>>(kvf, wo, wqt, wcf);
  gka_out<<<1024, 256, 0, stream>>>(seq, wcf, bo, out);
}

// Round 11
// 124.432 us; speedup vs baseline: 1.1357x; 1.1357x over previous
//
#include <hip/hip_runtime.h>
#include <hip/hip_bf16.h>
#include <stdint.h>

// Galerkin self-attention, fused:
//   out = seq @ (wq.T @ blockdiag_h(kv[b,h]) @ wo.T) + bo
//   kv[b,h] = (1/S) * LN(k)_h^T @ LN(v)_h,   k = seq@wk.T, v = seq@wv.T
// v11: r10's launch_bounds(256,4) spilled (merged GEMM live set ~208 regs in a
//      128 budget -> 268MB scratch). Fix: SPLIT k/v GEMM passes (peak live
//      ~115 regs, fits 128) keeping 32KB LDS + register LN + 2-phase outer
//      product -> genuine 4 blocks/CU for the latency-bound kv pass.
// ws layout (bytes):
//   0        wkf bf16 fragment-major [w8][kk][n][lane][8]
//   131072   wvf bf16 fragment-major
//   262144   wqT bf16 [256 i][256 j]        (written by gka_red blocks 0-15)
//   524288   kvf f32 [4 b][4 h][4096 frag]  (fragment order, by gka_red)
//   1310720  wcf bf16 fragment-major [b][o6][kk][n][lane][8]
// d_out doubles as scratch for P = bf16 partials [4 b][128 p][4 h][4096 frag]
// (16.8MB of the 33.5MB output buffer); gka_out fully overwrites d_out last.

#define EMBED 256
#define SEQ   8192
#define LN_EPS 1e-5f

using bf16x8 = __attribute__((ext_vector_type(8))) short;
using bf16x4 = __attribute__((ext_vector_type(4))) short;
using f32x4  = __attribute__((ext_vector_type(4))) float;

static __device__ __forceinline__ short f2bf(float f) {
  __hip_bfloat16 h = __float2bfloat16(f);
  return __builtin_bit_cast(short, h);
}
static __device__ __forceinline__ float bf2f(uint32_t u) {
  return __uint_as_float(u << 16);
}
static __device__ __forceinline__ bf16x8 cvt8(f32x4 a, f32x4 b) {
  bf16x8 v;
  v[0] = f2bf(a[0]); v[1] = f2bf(a[1]); v[2] = f2bf(a[2]); v[3] = f2bf(a[3]);
  v[4] = f2bf(b[0]); v[5] = f2bf(b[1]); v[6] = f2bf(b[2]); v[7] = f2bf(b[3]);
  return v;
}

#define MFMA16(a, b, c) __builtin_amdgcn_mfma_f32_16x16x32_bf16((a), (b), (c), 0, 0, 0)

// Stage ROWS x 256 fp32 rows -> bf16 LDS [ROWS][256], rows 512B, byte^=(row&7)<<4
template <int ROWS>
static __device__ __forceinline__ void stage_x(char* smem, const float* __restrict__ src, int tid) {
#pragma unroll
  for (int i = 0; i < ROWS / 8; ++i) {
    int g = tid + i * 256;              // 16B-granule index
    int row = g >> 5, c16 = g & 31;
    const f32x4* p = (const f32x4*)(src + row * EMBED + c16 * 8);
    *(bf16x8*)(smem + row * 512 + ((c16 * 16) ^ ((row & 7) << 4))) = cvt8(p[0], p[1]);
  }
}

// ---------------- prep: wk/wv -> fragment-major bf16 ----------------
__global__ void gka_prep(const float* __restrict__ wk, const float* __restrict__ wv,
                         unsigned short* __restrict__ wkf, unsigned short* __restrict__ wvf) {
  int blk = blockIdx.x, tid = threadIdx.x;
  int g = (blk & 31) * 256 + tid;         // [0, 8192) granule of 8 bf16
  const float* W = (blk < 32) ? wk : wv;
  unsigned short* D = (blk < 32) ? wkf : wvf;
  int w8 = g >> 11, kk = (g >> 8) & 7, n = (g >> 6) & 3, ln = g & 63;
  int row = w8 * 64 + n * 16 + (ln & 15);
  int c0 = kk * 32 + (ln >> 4) * 8;
  const f32x4* p = (const f32x4*)(W + row * 256 + c0);
  *(bf16x8*)(D + g * 8) = cvt8(p[0], p[1]);
}

// ---------------- pass A: k GEMM+LN, v GEMM+LN (split), 2-phase kv partial ----------
__global__ __launch_bounds__(256, 4)
void gka_kv(const float* __restrict__ seq,
            const unsigned short* __restrict__ wkf, const unsigned short* __restrict__ wvf,
            const float* __restrict__ lkg, const float* __restrict__ lkb,
            const float* __restrict__ lvg, const float* __restrict__ lvb,
            unsigned short* __restrict__ P) {
  __shared__ char smem[32768];            // x-tile; after GEMMs: [kT0 8K][vT0 8K][kT1 8K][vT1 8K]
  const int tid = threadIdx.x;
  const int lane = tid & 63;
  const int wid = tid >> 6;               // wave = head
  const int l15 = lane & 15, l4 = lane >> 4, l7 = lane & 7;
  const int tile = blockIdx.x;            // 512 blocks, 64 tokens each
  const int b = tile >> 7;
  const int ptile = tile & 127;

  stage_x<64>(smem, seq + (size_t)(b * SEQ + ptile * 64) * EMBED, tid);
  __syncthreads();

  // split k-pass then v-pass: one acc[4][4] live at a time (no spill at 128 regs)
  bf16x4 kln[16], vln[16];                // packed LN'd frags [m*4+n], 4 token-rows each
#pragma unroll
  for (int mat = 0; mat < 2; ++mat) {     // mat is unroll-static
    const unsigned short* Wf = mat ? wvf : wkf;
    const float* gp = mat ? lvg : lkg;
    const float* bp = mat ? lvb : lkb;
    float gv[4], bv[4];
#pragma unroll
    for (int n = 0; n < 4; ++n) { gv[n] = gp[n * 16 + l15]; bv[n] = bp[n * 16 + l15]; }

    f32x4 acc[4][4];
#pragma unroll
    for (int m = 0; m < 4; ++m)
#pragma unroll
      for (int n = 0; n < 4; ++n) acc[m][n] = (f32x4)0.0f;

#pragma unroll
    for (int kk = 0; kk < 8; ++kk) {      // K = 256, steps of 32
      bf16x8 af[4], bw[4];
#pragma unroll
      for (int m = 0; m < 4; ++m) {
        int row = m * 16 + l15;
        af[m] = *(const bf16x8*)(smem + row * 512 + ((kk * 64 + l4 * 16) ^ (l7 << 4)));
      }
#pragma unroll
      for (int n = 0; n < 4; ++n) {       // fragment-major: 512B coalesced per wave
        size_t off = (((wid * 8 + kk) * 4 + n) * 64 + lane) << 3;
        bw[n] = *(const bf16x8*)(Wf + off);
      }
#pragma unroll
      for (int m = 0; m < 4; ++m)
#pragma unroll
        for (int n = 0; n < 4; ++n)
          acc[m][n] = MFMA16(af[m], bw[n], acc[m][n]);
    }

    // LN over this wave's 64 head-cols -> packed registers
#pragma unroll
    for (int m = 0; m < 4; ++m) {
      float mu[4], rs[4];
#pragma unroll
      for (int r = 0; r < 4; ++r) {
        float s1 = 0.f, s2 = 0.f;
#pragma unroll
        for (int n = 0; n < 4; ++n) { float x = acc[m][n][r]; s1 += x; s2 += x * x; }
#pragma unroll
        for (int msk = 1; msk < 16; msk <<= 1) {
          s1 += __shfl_xor(s1, msk);
          s2 += __shfl_xor(s2, msk);
        }
        mu[r] = s1 * (1.f / 64.f);
        float var = s2 * (1.f / 64.f) - mu[r] * mu[r];
        rs[r] = rsqrtf(var + LN_EPS);
      }
#pragma unroll
      for (int n = 0; n < 4; ++n) {
        bf16x4 pk;
#pragma unroll
        for (int r = 0; r < 4; ++r)
          pk[r] = f2bf((acc[m][n][r] - mu[r]) * rs[r] * gv[n] + bv[n]);
        if (mat == 0) kln[m * 4 + n] = pk; else vln[m * 4 + n] = pk;
      }
    }
  }

  __syncthreads();                        // all x-tile LDS reads done; region reusable

  // kv partial: two phases, heads {0,1} then {2,3}; 32KB LDS total
#pragma unroll
  for (int p = 0; p < 2; ++p) {
    if ((wid >> 1) == p) {                // waves owning heads 2p, 2p+1 write tiles
      int hs = wid & 1;
#pragma unroll
      for (int m = 0; m < 4; ++m)
#pragma unroll
        for (int n = 0; n < 4; ++n) {
          int d = n * 16 + l15;           // d&7 == l7
          int sb = m * 32 + l4 * 8;       // byte in row, s0 = m*16 + l4*4
          int off = hs * 16384 + d * 128 + (sb ^ (l7 << 4));
          *(bf16x4*)(smem + off) = kln[m * 4 + n];
          *(bf16x4*)(smem + off + 8192) = vln[m * 4 + n];
        }
    }
    __syncthreads();
    int hs = wid >> 1;                    // head slot this wave computes
    int feh = wid & 1;                    // e-half
    f32x4 kvacc[4][2];
#pragma unroll
    for (int fd = 0; fd < 4; ++fd) { kvacc[fd][0] = (f32x4)0.0f; kvacc[fd][1] = (f32x4)0.0f; }
#pragma unroll
    for (int kk = 0; kk < 2; ++kk) {      // 64 tokens = 2 K-steps
      bf16x8 ak[4], b2[2];
#pragma unroll
      for (int fd = 0; fd < 4; ++fd) {
        int d = fd * 16 + l15;
        ak[fd] = *(const bf16x8*)(smem + hs * 16384 + d * 128 +
                                  ((kk * 64 + l4 * 16) ^ (l7 << 4)));
      }
#pragma unroll
      for (int c = 0; c < 2; ++c) {
        int e = (feh * 2 + c) * 16 + l15;
        b2[c] = *(const bf16x8*)(smem + hs * 16384 + 8192 + e * 128 +
                                 ((kk * 64 + l4 * 16) ^ (l7 << 4)));
      }
#pragma unroll
      for (int fd = 0; fd < 4; ++fd)
#pragma unroll
        for (int c = 0; c < 2; ++c)
          kvacc[fd][c] = MFMA16(ak[fd], b2[c], kvacc[fd][c]);
    }
    int hg = p * 2 + hs;
    // store P in fragment order (identical flat layout to r6): coalesced 512B
    unsigned short* Ph = P + ((size_t)((b * 128 + ptile) * 4 + hg) << 12);
#pragma unroll
    for (int fd = 0; fd < 4; ++fd)
#pragma unroll
      for (int c = 0; c < 2; ++c) {
        bf16x4 pk;
#pragma unroll
        for (int r = 0; r < 4; ++r) pk[r] = f2bf(kvacc[fd][c][r]);
        *(bf16x4*)(Ph + (fd * 4 + feh * 2 + c) * 256 + lane * 4) = pk;
      }
    __syncthreads();                      // before phase-1 overwrites tiles
  }
}

// ---------------- reduce: kvf = sum_p P;  blocks 0-15 also build wqT -----------------
__global__ __launch_bounds__(256)
void gka_red(const unsigned short* __restrict__ P, float* __restrict__ kvf,
             const float* __restrict__ wq, unsigned short* __restrict__ wqt) {
  __shared__ unsigned short T[64 * 66];
  int blk = blockIdx.x, tid = threadIdx.x;
  {
    int gtid = blk * 256 + tid;               // 131072 = 16384 quads x 8 chunks
    int chunk = gtid & 7;
    int qid = gtid >> 3;                      // (b<<12) | (h<<10) | t4
    int b = qid >> 12, h = (qid >> 10) & 3, t4 = qid & 1023;
    const unsigned short* p0 = P + ((size_t)(b * 512 + h) << 12) + t4 * 4;
    float s0 = 0.f, s1 = 0.f, s2 = 0.f, s3 = 0.f;
#pragma unroll
    for (int s = 0; s < 16; ++s) {
      int p = chunk * 16 + s;
      uint2 u = *(const uint2*)(p0 + ((size_t)p << 14));
      s0 += bf2f(u.x & 0xffffu); s1 += bf2f(u.x >> 16);
      s2 += bf2f(u.y & 0xffffu); s3 += bf2f(u.y >> 16);
    }
#pragma unroll
    for (int msk = 1; msk < 8; msk <<= 1) {
      s0 += __shfl_xor(s0, msk); s1 += __shfl_xor(s1, msk);
      s2 += __shfl_xor(s2, msk); s3 += __shfl_xor(s3, msk);
    }
    if (chunk == 0) {
      f32x4 r; r[0] = s0; r[1] = s1; r[2] = s2; r[3] = s3;
      *(f32x4*)(kvf + (qid << 2)) = r;
    }
  }

  if (blk < 16) {                         // 64x64 tile transpose wqt[i][j] = wq[j][i]
    int ti = blk >> 2, tj = blk & 3;
#pragma unroll
    for (int it = 0; it < 4; ++it) {
      int g = tid + it * 256;               // 1024 granules of 4 floats
      int jl = g >> 4, g4 = g & 15;
      f32x4 f = *(const f32x4*)(wq + (tj * 64 + jl) * 256 + ti * 64 + g4 * 4);
#pragma unroll
      for (int q = 0; q < 4; ++q) T[jl * 66 + g4 * 4 + q] = (unsigned short)f2bf(f[q]);
    }
    __syncthreads();
#pragma unroll
    for (int it = 0; it < 2; ++it) {
      int g = tid + it * 256;               // 512 output groups of 8
      int il = g >> 3, j8 = g & 7;
      bf16x8 v;
#pragma unroll
      for (int q = 0; q < 8; ++q) v[q] = (short)T[(j8 * 8 + q) * 66 + il];
      *(bf16x8*)(wqt + (ti * 64 + il) * 256 + tj * 64 + j8 * 8) = v;
    }
  }
}

// ---------------- pass B (merged m1+wc): per (b, o-half) block ----------------------
// phase 1: M1T[o_loc][j=h*64+d] = sum_e kv[b,h,d,e]/S * wo[o][h*64+e]  -> LDS (swz)
// phase 2: WcT frag-major: Wc[i][o] = sum_j wqT[i][j] * M1T[o_loc][j]
__global__ __launch_bounds__(512)
void gka_wc(const float* __restrict__ kvf, const float* __restrict__ wo,
            const unsigned short* __restrict__ wqt, unsigned short* __restrict__ wcf) {
  __shared__ char M1[65536];              // [128 o_loc][256 j] bf16, 512B rows, swz
  const int tid = threadIdx.x;
  const int lane = tid & 63;
  const int wid = tid >> 6;               // 8 waves
  const int l15 = lane & 15, l4 = lane >> 4;
  const int blk = blockIdx.x;             // 8 = 4b x 2 o-half
  const int b = blk >> 1, oh = blk & 1;
  const float invS = 1.f / (float)SEQ;

  // ---- phase 1: wave -> (wo_t = wid>>2 o-64-range, wj = wid&3 head) ----
  {
    const int wo_t = wid >> 2, wj = wid & 3;
    const float* kvh = kvf + ((b * 4 + wj) << 12);
    f32x4 acc[4][4];
#pragma unroll
    for (int m = 0; m < 4; ++m)
#pragma unroll
      for (int n = 0; n < 4; ++n) acc[m][n] = (f32x4)0.0f;

#pragma unroll
    for (int kk = 0; kk < 2; ++kk) {      // K = 64 (e)
      bf16x8 af[4], bw[4];
#pragma unroll
      for (int m = 0; m < 4; ++m) {
        // gather (d = m*16+l15, e = kk*32+l4*8+j) from kv fragment layout
        int base = (m * 4 + kk * 2 + (l4 >> 1)) * 256 +
                   ((l15 >> 2) * 16 + (l4 & 1) * 8) * 4 + (l15 & 3);
        bf16x8 v;
#pragma unroll
        for (int j = 0; j < 8; ++j) v[j] = f2bf(kvh[base + j * 4] * invS);
        af[m] = v;
      }
#pragma unroll
      for (int n = 0; n < 4; ++n) {
        int o = oh * 128 + wo_t * 64 + n * 16 + l15;
        const f32x4* wp = (const f32x4*)(wo + (size_t)o * 256 + wj * 64 + kk * 32 + l4 * 8);
        bw[n] = cvt8(wp[0], wp[1]);
      }
#pragma unroll
      for (int m = 0; m < 4; ++m)
#pragma unroll
        for (int n = 0; n < 4; ++n)
          acc[m][n] = MFMA16(af[m], bw[n], acc[m][n]);
    }
    // store to LDS M1T: row = o_loc, col j = wj*64 + m*16 + l4*4 + r (bf16x4), swz
#pragma unroll
    for (int m = 0; m < 4; ++m)
#pragma unroll
      for (int n = 0; n < 4; ++n) {
        int row = wo_t * 64 + n * 16 + l15;
        int jb = (wj * 64 + m * 16 + l4 * 4) * 2;
        bf16x4 pk;
#pragma unroll
        for (int r = 0; r < 4; ++r) pk[r] = f2bf(acc[m][n][r]);
        *(bf16x4*)(M1 + row * 512 + (jb ^ ((row & 7) << 4))) = pk;
      }
  }

  __syncthreads();

  // ---- phase 2: wave -> (wi = wid>>1 i-64-range, wo2 = wid&1 o-64-range) ----
  {
    const int wi = wid >> 1, wo2 = wid & 1;
    f32x4 acc[4][4];
#pragma unroll
    for (int m = 0; m < 4; ++m)
#pragma unroll
      for (int n = 0; n < 4; ++n) acc[m][n] = (f32x4)0.0f;

#pragma unroll
    for (int kk = 0; kk < 8; ++kk) {      // K = 256 (j)
      bf16x8 af[4], bw[4];
#pragma unroll
      for (int m = 0; m < 4; ++m) {
        int i = wi * 64 + m * 16 + l15;
        af[m] = *(const bf16x8*)(wqt + i * 256 + kk * 32 + l4 * 8);
      }
#pragma unroll
      for (int n = 0; n < 4; ++n) {
        int row = wo2 * 64 + n * 16 + l15;
        bw[n] = *(const bf16x8*)(M1 + row * 512 +
                                 ((kk * 64 + l4 * 16) ^ ((row & 7) << 4)));
      }
#pragma unroll
      for (int m = 0; m < 4; ++m)
#pragma unroll
        for (int n = 0; n < 4; ++n)
          acc[m][n] = MFMA16(af[m], bw[n], acc[m][n]);
    }
    // store to fragment-major wcf for gka_out
    const int o6 = oh * 2 + wo2;
#pragma unroll
    for (int m = 0; m < 4; ++m)
#pragma unroll
      for (int n = 0; n < 4; ++n) {
        int kko = wi * 2 + (m >> 1);
        int laneo = ((m & 1) * 2 + (l4 >> 1)) * 16 + l15;
        int jo = (l4 & 1) * 4;
        bf16x4 pk;
#pragma unroll
        for (int r = 0; r < 4; ++r) pk[r] = f2bf(acc[m][n][r]);
        *(bf16x4*)(wcf + ((size_t)b << 16) +
                   (((((o6 * 8 + kko) * 4 + n) * 64) + laneo) << 3) + jo) = pk;
      }
  }
}

// ---------------- pass C: out = seq @ Wc[b] + bo  (1024 x 32-token tiles, LDS) -------
__global__ __launch_bounds__(256, 4)
void gka_out(const float* __restrict__ seq, const unsigned short* __restrict__ wcf,
             const float* __restrict__ bo, float* __restrict__ out) {
  __shared__ char smem[16384];
  const int tid = threadIdx.x;
  const int lane = tid & 63;
  const int wid = tid >> 6;               // wave -> o-range (64 cols)
  const int l15 = lane & 15, l4 = lane >> 4, l7 = lane & 7;
  const int tile = blockIdx.x;            // 1024 = 4b x 256 tiles of 32 rows
  const int b = tile >> 8;
  const int srow = (tile & 255) * 32;

  stage_x<32>(smem, seq + (size_t)(b * SEQ + srow) * EMBED, tid);

  const unsigned short* Wf = wcf + ((size_t)b << 16);
  float bov[4];
#pragma unroll
  for (int n = 0; n < 4; ++n) bov[n] = bo[wid * 64 + n * 16 + l15];

  f32x4 acc[2][4];
#pragma unroll
  for (int m = 0; m < 2; ++m)
#pragma unroll
    for (int n = 0; n < 4; ++n) acc[m][n] = (f32x4)0.0f;

  __syncthreads();

#pragma unroll
  for (int kk = 0; kk < 8; ++kk) {        // K = 256, no barriers
    bf16x8 af[2], bw[4];
#pragma unroll
    for (int m = 0; m < 2; ++m) {
      int row = m * 16 + l15;
      af[m] = *(const bf16x8*)(smem + row * 512 + ((kk * 64 + l4 * 16) ^ (l7 << 4)));
    }
#pragma unroll
    for (int n = 0; n < 4; ++n)           // coalesced 512B per wave, L2-resident
      bw[n] = *(const bf16x8*)(Wf + ((((wid * 8 + kk) * 4 + n) * 64 + lane) << 3));
#pragma unroll
    for (int m = 0; m < 2; ++m)
#pragma unroll
      for (int n = 0; n < 4; ++n)
        acc[m][n] = MFMA16(af[m], bw[n], acc[m][n]);
  }

  float* dst = out + (size_t)(b * SEQ + srow) * EMBED;
#pragma unroll
  for (int m = 0; m < 2; ++m)
#pragma unroll
    for (int n = 0; n < 4; ++n)
#pragma unroll
      for (int r = 0; r < 4; ++r)
        dst[(size_t)(m * 16 + l4 * 4 + r) * EMBED + wid * 64 + n * 16 + l15] =
            acc[m][n][r] + bov[n];
}

extern "C" void kernel_launch(void* const* d_in, const int* in_sizes, int n_in,
                              void* d_out, int out_size, void* d_ws, size_t ws_size,
                              hipStream_t stream) {
  const float* seq = (const float*)d_in[0];
  const float* wq  = (const float*)d_in[1];
  const float* wk  = (const float*)d_in[2];
  const float* wv  = (const float*)d_in[3];
  const float* wo  = (const float*)d_in[4];
  const float* bo  = (const float*)d_in[5];
  const float* lkg = (const float*)d_in[6];
  const float* lkb = (const float*)d_in[7];
  const float* lvg = (const float*)d_in[8];
  const float* lvb = (const float*)d_in[9];
  float* out = (float*)d_out;
  char* ws = (char*)d_ws;

  unsigned short* wkf = (unsigned short*)(ws + 0);
  unsigned short* wvf = (unsigned short*)(ws + 131072);
  unsigned short* wqt = (unsigned short*)(ws + 262144);
  float*          kvf = (float*)(ws + 524288);
  unsigned short* wcf = (unsigned short*)(ws + 1310720);
  unsigned short* P   = (unsigned short*)d_out;   // 16.8MB partials, overwritten by gka_out

  gka_prep<<<64, 256, 0, stream>>>(wk, wv, wkf, wvf);
  gka_kv<<<512, 256, 0, stream>>>(seq, wkf, wvf, lkg, lkb, lvg, lvb, P);
  gka_red<<<512, 256, 0, stream>>>(P, kvf, wq, wqt);
  gka_wc<<<8, 512, 0, stream>>>(kvf, wo, wqt, wcf);
  gka_out<<<1024, 256, 0, stream>>>(seq, wcf, bo, out);
}

// Round 12
// 67.835 us; speedup vs baseline: 2.0832x; 1.8343x over previous
//
#include <hip/hip_runtime.h>
#include <hip/hip_bf16.h>
#include <stdint.h>

// Galerkin self-attention, fused:
//   out = seq @ (wq.T @ blockdiag_h(kv[b,h]) @ wo.T) + bo
//   kv[b,h] = (1/S) * LN(k)_h^T @ LN(v)_h,   k = seq@wk.T, v = seq@wv.T
// v12: kv reworked after two spill rounds (r10/r11: register-held LN frags =
//      64 VGPR pushed live set past the launch-bounds cap -> 230MB+ scratch).
//      Now: 8-wave (512-thr) blocks, 64KB LDS, 16 waves/CU (2x r6); split
//      k/v GEMM passes with acc[2][4] (32 regs) and LN written DIRECTLY to
//      LDS (kT upper 32K during k-pass; vT over dead x after sync); single-
//      phase outer product (wave = head x e-half). Peak live ~85 regs ->
//      (512,4) cap 128 safe. P layout bit-identical. Other kernels = r11.
// ws layout (bytes):
//   0        wkf bf16 fragment-major [w8][kk][n][lane][8]
//   131072   wvf bf16 fragment-major
//   262144   wqT bf16 [256 i][256 j]        (written by gka_red blocks 0-15)
//   524288   kvf f32 [4 b][4 h][4096 frag]  (fragment order, by gka_red)
//   1310720  wcf bf16 fragment-major [b][o6][kk][n][lane][8]
// d_out doubles as scratch for P = bf16 partials [4 b][128 p][4 h][4096 frag]
// (16.8MB of the 33.5MB output buffer); gka_out fully overwrites d_out last.

#define EMBED 256
#define SEQ   8192
#define LN_EPS 1e-5f

using bf16x8 = __attribute__((ext_vector_type(8))) short;
using bf16x4 = __attribute__((ext_vector_type(4))) short;
using f32x4  = __attribute__((ext_vector_type(4))) float;

static __device__ __forceinline__ short f2bf(float f) {
  __hip_bfloat16 h = __float2bfloat16(f);
  return __builtin_bit_cast(short, h);
}
static __device__ __forceinline__ float bf2f(uint32_t u) {
  return __uint_as_float(u << 16);
}
static __device__ __forceinline__ bf16x8 cvt8(f32x4 a, f32x4 b) {
  bf16x8 v;
  v[0] = f2bf(a[0]); v[1] = f2bf(a[1]); v[2] = f2bf(a[2]); v[3] = f2bf(a[3]);
  v[4] = f2bf(b[0]); v[5] = f2bf(b[1]); v[6] = f2bf(b[2]); v[7] = f2bf(b[3]);
  return v;
}

#define MFMA16(a, b, c) __builtin_amdgcn_mfma_f32_16x16x32_bf16((a), (b), (c), 0, 0, 0)

// Stage 32 x 256 fp32 rows -> bf16 LDS (256 threads), rows 512B, byte^=(row&7)<<4
static __device__ __forceinline__ void stage_x32(char* smem, const float* __restrict__ src, int tid) {
#pragma unroll
  for (int i = 0; i < 4; ++i) {
    int g = tid + i * 256;              // 16B-granule index
    int row = g >> 5, c16 = g & 31;
    const f32x4* p = (const f32x4*)(src + row * EMBED + c16 * 8);
    *(bf16x8*)(smem + row * 512 + ((c16 * 16) ^ ((row & 7) << 4))) = cvt8(p[0], p[1]);
  }
}

// ---------------- prep: wk/wv -> fragment-major bf16 ----------------
__global__ void gka_prep(const float* __restrict__ wk, const float* __restrict__ wv,
                         unsigned short* __restrict__ wkf, unsigned short* __restrict__ wvf) {
  int blk = blockIdx.x, tid = threadIdx.x;
  int g = (blk & 31) * 256 + tid;         // [0, 8192) granule of 8 bf16
  const float* W = (blk < 32) ? wk : wv;
  unsigned short* D = (blk < 32) ? wkf : wvf;
  int w8 = g >> 11, kk = (g >> 8) & 7, n = (g >> 6) & 3, ln = g & 63;
  int row = w8 * 64 + n * 16 + (ln & 15);
  int c0 = kk * 32 + (ln >> 4) * 8;
  const f32x4* p = (const f32x4*)(W + row * 256 + c0);
  *(bf16x8*)(D + g * 8) = cvt8(p[0], p[1]);
}

// ---------------- pass A: split k/v GEMM + LN->LDS + single-phase kv partial --------
// 8 waves: GEMM wave = (head h = wid&3, token-half mh = wid>>2), acc[2][4].
// LDS: [0,32K) x (later vT), [32K,64K) kT. Outer product wave = (h, e-half).
__global__ __launch_bounds__(512, 4)
void gka_kv(const float* __restrict__ seq,
            const unsigned short* __restrict__ wkf, const unsigned short* __restrict__ wvf,
            const float* __restrict__ lkg, const float* __restrict__ lkb,
            const float* __restrict__ lvg, const float* __restrict__ lvb,
            unsigned short* __restrict__ P) {
  __shared__ char smem[65536];
  const int tid = threadIdx.x;
  const int lane = tid & 63;
  const int wid = tid >> 6;               // 0..7
  const int h = wid & 3, mh = wid >> 2;
  const int l15 = lane & 15, l4 = lane >> 4, l7 = lane & 7;
  const int tile = blockIdx.x;            // 512 blocks, 64 tokens each
  const int b = tile >> 7;
  const int ptile = tile & 127;

  // stage x: 2048 granules / 512 threads
#pragma unroll
  for (int i = 0; i < 4; ++i) {
    int g = tid + i * 512;
    int row = g >> 5, c16 = g & 31;
    const f32x4* p = (const f32x4*)(seq + (size_t)(b * SEQ + ptile * 64 + row) * EMBED + c16 * 8);
    *(bf16x8*)(smem + row * 512 + ((c16 * 16) ^ ((row & 7) << 4))) = cvt8(p[0], p[1]);
  }
  __syncthreads();

#pragma unroll
  for (int mat = 0; mat < 2; ++mat) {     // 0: k -> kT @32K; 1: v -> vT @0 (over x)
    const unsigned short* Wf = mat ? wvf : wkf;
    const float* gp = mat ? lvg : lkg;
    const float* bp = mat ? lvb : lkb;
    float gv[4], bv[4];
#pragma unroll
    for (int n = 0; n < 4; ++n) { gv[n] = gp[n * 16 + l15]; bv[n] = bp[n * 16 + l15]; }

    f32x4 acc[2][4];
#pragma unroll
    for (int m = 0; m < 2; ++m)
#pragma unroll
      for (int n = 0; n < 4; ++n) acc[m][n] = (f32x4)0.0f;

#pragma unroll
    for (int kk = 0; kk < 8; ++kk) {      // K = 256, steps of 32
      bf16x8 af[2], bw[4];
#pragma unroll
      for (int m = 0; m < 2; ++m) {
        int row = mh * 32 + m * 16 + l15;
        af[m] = *(const bf16x8*)(smem + row * 512 + ((kk * 64 + l4 * 16) ^ (l7 << 4)));
      }
#pragma unroll
      for (int n = 0; n < 4; ++n) {       // fragment-major: 512B coalesced per wave
        size_t off = (((h * 8 + kk) * 4 + n) * 64 + lane) << 3;
        bw[n] = *(const bf16x8*)(Wf + off);
      }
#pragma unroll
      for (int m = 0; m < 2; ++m)
#pragma unroll
        for (int n = 0; n < 4; ++n)
          acc[m][n] = MFMA16(af[m], bw[n], acc[m][n]);
    }

    if (mat == 1) __syncthreads();        // ALL x reads done before vT overwrites x

    // LN over this wave's 32 token-rows x 64 head-cols; write transposed to LDS
    char* T = smem + (mat ? 0 : 32768) + h * 8192;   // [64 d|e][64 s], 128B rows, swz
#pragma unroll
    for (int m = 0; m < 2; ++m) {
      float mu[4], rs[4];
#pragma unroll
      for (int r = 0; r < 4; ++r) {
        float s1 = 0.f, s2 = 0.f;
#pragma unroll
        for (int n = 0; n < 4; ++n) { float x = acc[m][n][r]; s1 += x; s2 += x * x; }
#pragma unroll
        for (int msk = 1; msk < 16; msk <<= 1) {
          s1 += __shfl_xor(s1, msk);
          s2 += __shfl_xor(s2, msk);
        }
        mu[r] = s1 * (1.f / 64.f);
        float var = s2 * (1.f / 64.f) - mu[r] * mu[r];
        rs[r] = rsqrtf(var + LN_EPS);
      }
#pragma unroll
      for (int n = 0; n < 4; ++n) {
        bf16x4 pk;
#pragma unroll
        for (int r = 0; r < 4; ++r)
          pk[r] = f2bf((acc[m][n][r] - mu[r]) * rs[r] * gv[n] + bv[n]);
        int d = n * 16 + l15;             // d&7 == l7
        int sb = mh * 64 + m * 32 + l4 * 8;   // byte of s0 = mh*32 + m*16 + l4*4
        *(bf16x4*)(T + d * 128 + (sb ^ (l7 << 4))) = pk;
      }
    }
  }

  __syncthreads();                        // kT + vT ready

  // kv outer product: wave = (head h, e-half eh=mh); kv[d][e] += sum_s kT[d][s]*vT[e][s]
  {
    const int eh = mh;
    f32x4 kvacc[4][2];
#pragma unroll
    for (int fd = 0; fd < 4; ++fd) { kvacc[fd][0] = (f32x4)0.0f; kvacc[fd][1] = (f32x4)0.0f; }
#pragma unroll
    for (int kk = 0; kk < 2; ++kk) {      // 64 tokens = 2 K-steps
      bf16x8 ak[4], b2[2];
#pragma unroll
      for (int fd = 0; fd < 4; ++fd) {
        int d = fd * 16 + l15;
        ak[fd] = *(const bf16x8*)(smem + 32768 + h * 8192 + d * 128 +
                                  ((kk * 64 + l4 * 16) ^ (l7 << 4)));
      }
#pragma unroll
      for (int c = 0; c < 2; ++c) {
        int e = (eh * 2 + c) * 16 + l15;
        b2[c] = *(const bf16x8*)(smem + h * 8192 + e * 128 +
                                 ((kk * 64 + l4 * 16) ^ (l7 << 4)));
      }
#pragma unroll
      for (int fd = 0; fd < 4; ++fd)
#pragma unroll
        for (int c = 0; c < 2; ++c)
          kvacc[fd][c] = MFMA16(ak[fd], b2[c], kvacc[fd][c]);
    }
    // store P in fragment order (flat layout identical to r6): coalesced 512B
    unsigned short* Ph = P + ((size_t)((b * 128 + ptile) * 4 + h) << 12);
#pragma unroll
    for (int fd = 0; fd < 4; ++fd)
#pragma unroll
      for (int c = 0; c < 2; ++c) {
        bf16x4 pk;
#pragma unroll
        for (int r = 0; r < 4; ++r) pk[r] = f2bf(kvacc[fd][c][r]);
        *(bf16x4*)(Ph + (fd * 4 + eh * 2 + c) * 256 + lane * 4) = pk;
      }
  }
}

// ---------------- reduce: kvf = sum_p P;  blocks 0-15 also build wqT -----------------
__global__ __launch_bounds__(256)
void gka_red(const unsigned short* __restrict__ P, float* __restrict__ kvf,
             const float* __restrict__ wq, unsigned short* __restrict__ wqt) {
  __shared__ unsigned short T[64 * 66];
  int blk = blockIdx.x, tid = threadIdx.x;
  {
    int gtid = blk * 256 + tid;               // 131072 = 16384 quads x 8 chunks
    int chunk = gtid & 7;
    int qid = gtid >> 3;                      // (b<<12) | (h<<10) | t4
    int b = qid >> 12, h = (qid >> 10) & 3, t4 = qid & 1023;
    const unsigned short* p0 = P + ((size_t)(b * 512 + h) << 12) + t4 * 4;
    float s0 = 0.f, s1 = 0.f, s2 = 0.f, s3 = 0.f;
#pragma unroll
    for (int s = 0; s < 16; ++s) {
      int p = chunk * 16 + s;
      uint2 u = *(const uint2*)(p0 + ((size_t)p << 14));
      s0 += bf2f(u.x & 0xffffu); s1 += bf2f(u.x >> 16);
      s2 += bf2f(u.y & 0xffffu); s3 += bf2f(u.y >> 16);
    }
#pragma unroll
    for (int msk = 1; msk < 8; msk <<= 1) {
      s0 += __shfl_xor(s0, msk); s1 += __shfl_xor(s1, msk);
      s2 += __shfl_xor(s2, msk); s3 += __shfl_xor(s3, msk);
    }
    if (chunk == 0) {
      f32x4 r; r[0] = s0; r[1] = s1; r[2] = s2; r[3] = s3;
      *(f32x4*)(kvf + (qid << 2)) = r;
    }
  }

  if (blk < 16) {                         // 64x64 tile transpose wqt[i][j] = wq[j][i]
    int ti = blk >> 2, tj = blk & 3;
#pragma unroll
    for (int it = 0; it < 4; ++it) {
      int g = tid + it * 256;               // 1024 granules of 4 floats
      int jl = g >> 4, g4 = g & 15;
      f32x4 f = *(const f32x4*)(wq + (tj * 64 + jl) * 256 + ti * 64 + g4 * 4);
#pragma unroll
      for (int q = 0; q < 4; ++q) T[jl * 66 + g4 * 4 + q] = (unsigned short)f2bf(f[q]);
    }
    __syncthreads();
#pragma unroll
    for (int it = 0; it < 2; ++it) {
      int g = tid + it * 256;               // 512 output groups of 8
      int il = g >> 3, j8 = g & 7;
      bf16x8 v;
#pragma unroll
      for (int q = 0; q < 8; ++q) v[q] = (short)T[(j8 * 8 + q) * 66 + il];
      *(bf16x8*)(wqt + (ti * 64 + il) * 256 + tj * 64 + j8 * 8) = v;
    }
  }
}

// ---------------- pass B (merged m1+wc): per (b, o-half) block ----------------------
// phase 1: M1T[o_loc][j=h*64+d] = sum_e kv[b,h,d,e]/S * wo[o][h*64+e]  -> LDS (swz)
// phase 2: WcT frag-major: Wc[i][o] = sum_j wqT[i][j] * M1T[o_loc][j]
__global__ __launch_bounds__(512)
void gka_wc(const float* __restrict__ kvf, const float* __restrict__ wo,
            const unsigned short* __restrict__ wqt, unsigned short* __restrict__ wcf) {
  __shared__ char M1[65536];              // [128 o_loc][256 j] bf16, 512B rows, swz
  const int tid = threadIdx.x;
  const int lane = tid & 63;
  const int wid = tid >> 6;               // 8 waves
  const int l15 = lane & 15, l4 = lane >> 4;
  const int blk = blockIdx.x;             // 8 = 4b x 2 o-half
  const int b = blk >> 1, oh = blk & 1;
  const float invS = 1.f / (float)SEQ;

  // ---- phase 1: wave -> (wo_t = wid>>2 o-64-range, wj = wid&3 head) ----
  {
    const int wo_t = wid >> 2, wj = wid & 3;
    const float* kvh = kvf + ((b * 4 + wj) << 12);
    f32x4 acc[4][4];
#pragma unroll
    for (int m = 0; m < 4; ++m)
#pragma unroll
      for (int n = 0; n < 4; ++n) acc[m][n] = (f32x4)0.0f;

#pragma unroll
    for (int kk = 0; kk < 2; ++kk) {      // K = 64 (e)
      bf16x8 af[4], bw[4];
#pragma unroll
      for (int m = 0; m < 4; ++m) {
        // gather (d = m*16+l15, e = kk*32+l4*8+j) from kv fragment layout
        int base = (m * 4 + kk * 2 + (l4 >> 1)) * 256 +
                   ((l15 >> 2) * 16 + (l4 & 1) * 8) * 4 + (l15 & 3);
        bf16x8 v;
#pragma unroll
        for (int j = 0; j < 8; ++j) v[j] = f2bf(kvh[base + j * 4] * invS);
        af[m] = v;
      }
#pragma unroll
      for (int n = 0; n < 4; ++n) {
        int o = oh * 128 + wo_t * 64 + n * 16 + l15;
        const f32x4* wp = (const f32x4*)(wo + (size_t)o * 256 + wj * 64 + kk * 32 + l4 * 8);
        bw[n] = cvt8(wp[0], wp[1]);
      }
#pragma unroll
      for (int m = 0; m < 4; ++m)
#pragma unroll
        for (int n = 0; n < 4; ++n)
          acc[m][n] = MFMA16(af[m], bw[n], acc[m][n]);
    }
    // store to LDS M1T: row = o_loc, col j = wj*64 + m*16 + l4*4 + r (bf16x4), swz
#pragma unroll
    for (int m = 0; m < 4; ++m)
#pragma unroll
      for (int n = 0; n < 4; ++n) {
        int row = wo_t * 64 + n * 16 + l15;
        int jb = (wj * 64 + m * 16 + l4 * 4) * 2;
        bf16x4 pk;
#pragma unroll
        for (int r = 0; r < 4; ++r) pk[r] = f2bf(acc[m][n][r]);
        *(bf16x4*)(M1 + row * 512 + (jb ^ ((row & 7) << 4))) = pk;
      }
  }

  __syncthreads();

  // ---- phase 2: wave -> (wi = wid>>1 i-64-range, wo2 = wid&1 o-64-range) ----
  {
    const int wi = wid >> 1, wo2 = wid & 1;
    f32x4 acc[4][4];
#pragma unroll
    for (int m = 0; m < 4; ++m)
#pragma unroll
      for (int n = 0; n < 4; ++n) acc[m][n] = (f32x4)0.0f;

#pragma unroll
    for (int kk = 0; kk < 8; ++kk) {      // K = 256 (j)
      bf16x8 af[4], bw[4];
#pragma unroll
      for (int m = 0; m < 4; ++m) {
        int i = wi * 64 + m * 16 + l15;
        af[m] = *(const bf16x8*)(wqt + i * 256 + kk * 32 + l4 * 8);
      }
#pragma unroll
      for (int n = 0; n < 4; ++n) {
        int row = wo2 * 64 + n * 16 + l15;
        bw[n] = *(const bf16x8*)(M1 + row * 512 +
                                 ((kk * 64 + l4 * 16) ^ ((row & 7) << 4)));
      }
#pragma unroll
      for (int m = 0; m < 4; ++m)
#pragma unroll
        for (int n = 0; n < 4; ++n)
          acc[m][n] = MFMA16(af[m], bw[n], acc[m][n]);
    }
    // store to fragment-major wcf for gka_out
    const int o6 = oh * 2 + wo2;
#pragma unroll
    for (int m = 0; m < 4; ++m)
#pragma unroll
      for (int n = 0; n < 4; ++n) {
        int kko = wi * 2 + (m >> 1);
        int laneo = ((m & 1) * 2 + (l4 >> 1)) * 16 + l15;
        int jo = (l4 & 1) * 4;
        bf16x4 pk;
#pragma unroll
        for (int r = 0; r < 4; ++r) pk[r] = f2bf(acc[m][n][r]);
        *(bf16x4*)(wcf + ((size_t)b << 16) +
                   (((((o6 * 8 + kko) * 4 + n) * 64) + laneo) << 3) + jo) = pk;
      }
  }
}

// ---------------- pass C: out = seq @ Wc[b] + bo  (1024 x 32-token tiles, LDS) -------
__global__ __launch_bounds__(256, 4)
void gka_out(const float* __restrict__ seq, const unsigned short* __restrict__ wcf,
             const float* __restrict__ bo, float* __restrict__ out) {
  __shared__ char smem[16384];
  const int tid = threadIdx.x;
  const int lane = tid & 63;
  const int wid = tid >> 6;               // wave -> o-range (64 cols)
  const int l15 = lane & 15, l4 = lane >> 4, l7 = lane & 7;
  const int tile = blockIdx.x;            // 1024 = 4b x 256 tiles of 32 rows
  const int b = tile >> 8;
  const int srow = (tile & 255) * 32;

  stage_x32(smem, seq + (size_t)(b * SEQ + srow) * EMBED, tid);

  const unsigned short* Wf = wcf + ((size_t)b << 16);
  float bov[4];
#pragma unroll
  for (int n = 0; n < 4; ++n) bov[n] = bo[wid * 64 + n * 16 + l15];

  f32x4 acc[2][4];
#pragma unroll
  for (int m = 0; m < 2; ++m)
#pragma unroll
    for (int n = 0; n < 4; ++n) acc[m][n] = (f32x4)0.0f;

  __syncthreads();

#pragma unroll
  for (int kk = 0; kk < 8; ++kk) {        // K = 256, no barriers
    bf16x8 af[2], bw[4];
#pragma unroll
    for (int m = 0; m < 2; ++m) {
      int row = m * 16 + l15;
      af[m] = *(const bf16x8*)(smem + row * 512 + ((kk * 64 + l4 * 16) ^ (l7 << 4)));
    }
#pragma unroll
    for (int n = 0; n < 4; ++n)           // coalesced 512B per wave, L2-resident
      bw[n] = *(const bf16x8*)(Wf + ((((wid * 8 + kk) * 4 + n) * 64 + lane) << 3));
#pragma unroll
    for (int m = 0; m < 2; ++m)
#pragma unroll
      for (int n = 0; n < 4; ++n)
        acc[m][n] = MFMA16(af[m], bw[n], acc[m][n]);
  }

  float* dst = out + (size_t)(b * SEQ + srow) * EMBED;
#pragma unroll
  for (int m = 0; m < 2; ++m)
#pragma unroll
    for (int n = 0; n < 4; ++n)
#pragma unroll
      for (int r = 0; r < 4; ++r)
        dst[(size_t)(m * 16 + l4 * 4 + r) * EMBED + wid * 64 + n * 16 + l15] =
            acc[m][n][r] + bov[n];
}

extern "C" void kernel_launch(void* const* d_in, const int* in_sizes, int n_in,
                              void* d_out, int out_size, void* d_ws, size_t ws_size,
                              hipStream_t stream) {
  const float* seq = (const float*)d_in[0];
  const float* wq  = (const float*)d_in[1];
  const float* wk  = (const float*)d_in[2];
  const float* wv  = (const float*)d_in[3];
  const float* wo  = (const float*)d_in[4];
  const float* bo  = (const float*)d_in[5];
  const float* lkg = (const float*)d_in[6];
  const float* lkb = (const float*)d_in[7];
  const float* lvg = (const float*)d_in[8];
  const float* lvb = (const float*)d_in[9];
  float* out = (float*)d_out;
  char* ws = (char*)d_ws;

  unsigned short* wkf = (unsigned short*)(ws + 0);
  unsigned short* wvf = (unsigned short*)(ws + 131072);
  unsigned short* wqt = (unsigned short*)(ws + 262144);
  float*          kvf = (float*)(ws + 524288);
  unsigned short* wcf = (unsigned short*)(ws + 1310720);
  unsigned short* P   = (unsigned short*)d_out;   // 16.8MB partials, overwritten by gka_out

  gka_prep<<<64, 256, 0, stream>>>(wk, wv, wkf, wvf);
  gka_kv<<<512, 512, 0, stream>>>(seq, wkf, wvf, lkg, lkb, lvg, lvb, P);
  gka_red<<<512, 256, 0, stream>>>(P, kvf, wq, wqt);
  gka_wc<<<8, 512, 0, stream>>>(kvf, wo, wqt, wcf);
  gka_out<<<1024, 256, 0, stream>>>(seq, wcf, bo, out);
}